// Round 9
// baseline (177.350 us; speedup 1.0000x reference)
//
#include <hip/hip_runtime.h>
#include <hip/hip_bf16.h>
#include <hip/hip_fp16.h>
#include <math.h>

#define NB 64
#define CC 512
#define LL 256

typedef __attribute__((ext_vector_type(4))) float floatx4;
typedef __attribute__((ext_vector_type(8))) short short8;

static __device__ __forceinline__ unsigned f2bf2(float x, float y) {
    __hip_bfloat162 h = __float22bfloat162_rn(make_float2(x, y));
    union { __hip_bfloat162 h; unsigned u; } c; c.h = h;
    return c.u;   // low 16 = x, high 16 = y
}
static __device__ __forceinline__ unsigned f2h(float x) {
    __half h = __float2half_rn(x);
    union { __half h; unsigned short u; } c; c.h = h;
    return (unsigned)c.u;
}
static __device__ __forceinline__ float h2f(unsigned u) {
    union { unsigned short u; __half h; } c; c.u = (unsigned short)u;
    return __half2float(c.h);
}

// ---------------- K1: compact + fp32->bf16 convert of positive rows + norms ----------
// grid (8, NB), 256 threads. Block (g, n): ballot-compacts batch n (all 8 blocks do it
// redundantly, cheap), g==0 also writes idx/npos and zeroes sums/out, then converts
// compacted rows [g*64, min(np,(g+1)*64)) of S and T to bf16 + squared norms.
__global__ __launch_bounds__(256) void prep_kernel(
    const float* __restrict__ S, const float* __restrict__ T,
    const int* __restrict__ targets,
    int* __restrict__ idx, int* __restrict__ npos,
    float* __restrict__ sumS, float* __restrict__ sumT, float* __restrict__ out,
    unsigned short* __restrict__ Ps, unsigned short* __restrict__ Pt,
    float* __restrict__ ns, float* __restrict__ nt)
{
    const int g = blockIdx.x, n = blockIdx.y;
    __shared__ int s_idx[CC];
    __shared__ int s_cnt[8], s_off[8];
    __shared__ int s_npS;

    const int tid = threadIdx.x;
    const int w = tid >> 6, lane = tid & 63;

    const int* tg = targets + n * CC;
    const bool p0 = tg[tid] != 0;
    const bool p1 = tg[tid + 256] != 0;
    const unsigned long long m0 = __ballot(p0);
    const unsigned long long m1 = __ballot(p1);
    if (lane == 0) { s_cnt[w] = __popcll(m0); s_cnt[4 + w] = __popcll(m1); }
    __syncthreads();
    if (tid == 0) {
        int a = 0;
        for (int i = 0; i < 8; ++i) { s_off[i] = a; a += s_cnt[i]; }
        s_npS = a;
    }
    __syncthreads();
    const unsigned long long below = (1ull << lane) - 1ull;
    if (p0) s_idx[s_off[w] + __popcll(m0 & below)] = tid;
    if (p1) s_idx[s_off[4 + w] + __popcll(m1 & below)] = tid + 256;
    __syncthreads();
    const int np = s_npS;

    if (g == 0) {
        for (int k = tid; k < np; k += 256) idx[n * CC + k] = s_idx[k];
        if (tid == 0) {
            npos[n] = np;
            sumS[n] = 0.0f; sumT[n] = 0.0f;
            if (n == 0) out[0] = 0.0f;
        }
    }

    // convert rows: one wave per row, 64 lanes x float4 == 256 floats
    const int kend = min(np, (g + 1) * 64);
    for (int k = g * 64 + w; k < kend; k += 4) {
        const int r = s_idx[k];
        const float4 a = ((const float4*)(S + ((size_t)n * CC + r) * LL))[lane];
        const float4 b = ((const float4*)(T + ((size_t)n * CC + r) * LL))[lane];
        const size_t dst = ((size_t)n * CC + k) * LL + lane * 4;
        *(uint2*)&Ps[dst] = make_uint2(f2bf2(a.x, a.y), f2bf2(a.z, a.w));
        *(uint2*)&Pt[dst] = make_uint2(f2bf2(b.x, b.y), f2bf2(b.z, b.w));
        float vs = a.x * a.x + a.y * a.y + a.z * a.z + a.w * a.w;
        float vt = b.x * b.x + b.y * b.y + b.z * b.z + b.w * b.w;
        #pragma unroll
        for (int o = 32; o; o >>= 1) { vs += __shfl_down(vs, o); vt += __shfl_down(vt, o); }
        if (lane == 0) { ns[n * CC + k] = vs; nt[n * CC + k] = vt; }
    }
}

// ---------------- K2: 32x32 MFMA distance tiles, single wave, no LDS, no barriers ----
// bx = lin*64 + n (XCD-clustered). Fragments loaded straight from bf16 global:
// A/B layout [m=lane&15][k=quad*8+j] -> one dwordx4 per fragment, fully dense lines.
__global__ __launch_bounds__(64) void dist_kernel(
    const unsigned short* __restrict__ Ps, const unsigned short* __restrict__ Pt,
    const float* __restrict__ ns, const float* __restrict__ nt,
    const int* __restrict__ npos,
    float* __restrict__ sumS, float* __restrict__ sumT,
    unsigned* __restrict__ D)
{
    const int bx = blockIdx.x;
    const int n = bx & (NB - 1), lin = bx >> 6;
    int tI = 0, rem = lin;                    // linear -> upper-tri (tI,tJ) of 16x16
    while (rem >= 16 - tI) { rem -= 16 - tI; ++tI; }
    const int tJ = tI + rem;
    const bool diag = (tI == tJ);

    const int np = npos[n];
    if (np < 2 || tI * 32 >= np || tJ * 32 >= np) return;

    const int lane = threadIdx.x;
    const int m16 = lane & 15, quad = lane >> 4;

    // clamped fragment rows (rows >= np alias np-1; masked in epilogue)
    const int rA0 = min(tI * 32 + m16, np - 1);
    const int rA1 = min(tI * 32 + 16 + m16, np - 1);
    const int rB0 = min(tJ * 32 + m16, np - 1);
    const int rB1 = min(tJ * 32 + 16 + m16, np - 1);
    const size_t base = (size_t)n * CC * LL + quad * 8;
    const unsigned short* a0s = Ps + base + (size_t)rA0 * LL;
    const unsigned short* a1s = Ps + base + (size_t)rA1 * LL;
    const unsigned short* b0s = Ps + base + (size_t)rB0 * LL;
    const unsigned short* b1s = Ps + base + (size_t)rB1 * LL;
    const unsigned short* a0t = Pt + base + (size_t)rA0 * LL;
    const unsigned short* a1t = Pt + base + (size_t)rA1 * LL;
    const unsigned short* b0t = Pt + base + (size_t)rB0 * LL;
    const unsigned short* b1t = Pt + base + (size_t)rB1 * LL;

    floatx4 accS[4], accT[4];                 // [qi*2+qj]
    #pragma unroll
    for (int q = 0; q < 4; ++q) {
        accS[q][0] = 0; accS[q][1] = 0; accS[q][2] = 0; accS[q][3] = 0;
        accT[q][0] = 0; accT[q][1] = 0; accT[q][2] = 0; accT[q][3] = 0;
    }

    #pragma unroll 2
    for (int kk = 0; kk < 8; ++kk) {
        const int o = kk * 32;                // halves
        const short8 fa0s = *(const short8*)(a0s + o);
        const short8 fa1s = *(const short8*)(a1s + o);
        const short8 fb0s = *(const short8*)(b0s + o);
        const short8 fb1s = *(const short8*)(b1s + o);
        const short8 fa0t = *(const short8*)(a0t + o);
        const short8 fa1t = *(const short8*)(a1t + o);
        const short8 fb0t = *(const short8*)(b0t + o);
        const short8 fb1t = *(const short8*)(b1t + o);
        accS[0] = __builtin_amdgcn_mfma_f32_16x16x32_bf16(fa0s, fb0s, accS[0], 0, 0, 0);
        accS[1] = __builtin_amdgcn_mfma_f32_16x16x32_bf16(fa0s, fb1s, accS[1], 0, 0, 0);
        accS[2] = __builtin_amdgcn_mfma_f32_16x16x32_bf16(fa1s, fb0s, accS[2], 0, 0, 0);
        accS[3] = __builtin_amdgcn_mfma_f32_16x16x32_bf16(fa1s, fb1s, accS[3], 0, 0, 0);
        accT[0] = __builtin_amdgcn_mfma_f32_16x16x32_bf16(fa0t, fb0t, accT[0], 0, 0, 0);
        accT[1] = __builtin_amdgcn_mfma_f32_16x16x32_bf16(fa0t, fb1t, accT[1], 0, 0, 0);
        accT[2] = __builtin_amdgcn_mfma_f32_16x16x32_bf16(fa1t, fb0t, accT[2], 0, 0, 0);
        accT[3] = __builtin_amdgcn_mfma_f32_16x16x32_bf16(fa1t, fb1t, accT[3], 0, 0, 0);
    }

    // ---- epilogue; C/D layout: col=lane&15, row=quad*4+reg ----
    float nsR[8], ntR[8];                     // row norms, [qi*4 + r]
    #pragma unroll
    for (int qi = 0; qi < 2; ++qi)
        #pragma unroll
        for (int r = 0; r < 4; ++r) {
            const int gi = min(tI * 32 + qi * 16 + quad * 4 + r, np - 1);
            nsR[qi * 4 + r] = ns[n * CC + gi];
            ntR[qi * 4 + r] = nt[n * CC + gi];
        }
    float nsC[2], ntC[2];                     // col norms, [qj]
    #pragma unroll
    for (int qj = 0; qj < 2; ++qj) {
        const int gj = min(tJ * 32 + qj * 16 + m16, np - 1);
        nsC[qj] = ns[n * CC + gj];
        ntC[qj] = nt[n * CC + gj];
    }

    unsigned* Dn = D + ((size_t)bx << 10);    // 32x32 entries
    float l0 = 0.0f, l1 = 0.0f;
    #pragma unroll
    for (int qi = 0; qi < 2; ++qi)
        #pragma unroll
        for (int qj = 0; qj < 2; ++qj) {
            const int q = qi * 2 + qj;
            const int colL = qj * 16 + m16;
            const int gj = tJ * 32 + colL;
            #pragma unroll
            for (int r = 0; r < 4; ++r) {
                const int rowL = qi * 16 + quad * 4 + r;
                const int gi = tI * 32 + rowL;
                const float ds = sqrtf(fmaxf(nsR[qi * 4 + r] + nsC[qj] - 2.0f * accS[q][r], 1e-12f));
                const float dt = sqrtf(fmaxf(ntR[qi * 4 + r] + ntC[qj] - 2.0f * accT[q][r], 1e-12f));
                if (gi < np && gj < np && gi != gj) { l0 += ds; l1 += dt; }
                Dn[rowL * 32 + colL] = f2h(ds) | (f2h(dt) << 16);
            }
        }

    #pragma unroll
    for (int o = 32; o; o >>= 1) { l0 += __shfl_down(l0, o); l1 += __shfl_down(l1, o); }
    if (lane == 0) {
        const float wgt = diag ? 1.0f : 2.0f; // off-diag tiles mirror-counted
        atomicAdd(&sumS[n], wgt * l0);
        atomicAdd(&sumT[n], wgt * l1);
    }
}

// ---------------- K3: streaming Huber over packed (ds, dt) ----------------
__global__ __launch_bounds__(64) void huber_kernel(
    const unsigned* __restrict__ D, const int* __restrict__ npos,
    const float* __restrict__ sumS, const float* __restrict__ sumT,
    float* __restrict__ out)
{
    const int bx = blockIdx.x;
    const int n = bx & (NB - 1), lin = bx >> 6;
    int tI = 0, rem = lin;
    while (rem >= 16 - tI) { rem -= 16 - tI; ++tI; }
    const int tJ = tI + rem;

    const int np = npos[n];
    if (np < 2 || tI * 32 >= np || tJ * 32 >= np) return;

    const float cnt = (float)np * (float)(np - 1);
    const float inv_ms = cnt / sumS[n];
    const float inv_mt = cnt / sumT[n];

    const uint4* Dn = (const uint4*)(D + ((size_t)bx << 10));
    const int lane = threadIdx.x;

    float h = 0.0f;
    #pragma unroll
    for (int it = 0; it < 4; ++it) {
        const int e4 = it * 64 + lane;        // uint4 index; element = e4*4
        const uint4 v = Dn[e4];
        const unsigned vv[4] = { v.x, v.y, v.z, v.w };
        const int e0 = e4 * 4;
        #pragma unroll
        for (int k = 0; k < 4; ++k) {
            const int e = e0 + k;
            const int gi = tI * 32 + (e >> 5);
            const int gj = tJ * 32 + (e & 31);
            if (gi < np && gj < np && gi != gj) {
                const float ds = h2f(vv[k] & 0xffffu);
                const float dt = h2f(vv[k] >> 16);
                const float diff = ds * inv_ms - dt * inv_mt;
                const float ad = fabsf(diff);
                h += (ad < 1.0f) ? 0.5f * diff * diff : ad - 0.5f;
            }
        }
    }

    #pragma unroll
    for (int o = 32; o; o >>= 1) h += __shfl_down(h, o);
    if (lane == 0) {
        const float wgt = (tI == tJ) ? 1.0f : 2.0f;
        atomicAdd(out, wgt * h / (float)np);
    }
}

extern "C" void kernel_launch(void* const* d_in, const int* in_sizes, int n_in,
                              void* d_out, int out_size, void* d_ws, size_t ws_size,
                              hipStream_t stream) {
    const float* S = (const float*)d_in[0];
    const float* T = (const float*)d_in[1];
    const int* targets = (const int*)d_in[2];
    float* out = (float*)d_out;

    char* p = (char*)d_ws;
    int* idx = (int*)p;                  p += (size_t)NB * CC * 4;
    int* npos = (int*)p;                 p += NB * 4;
    float* sumS = (float*)p;             p += NB * 4;
    float* sumT = (float*)p;             p += NB * 4;
    float* ns = (float*)p;               p += (size_t)NB * CC * 4;
    float* nt = (float*)p;               p += (size_t)NB * CC * 4;
    p = (char*)(((size_t)p + 255) & ~(size_t)255);
    unsigned short* Ps = (unsigned short*)p;  p += (size_t)NB * CC * LL * 2;  // 16.8 MB
    unsigned short* Pt = (unsigned short*)p;  p += (size_t)NB * CC * LL * 2;  // 16.8 MB
    unsigned* D = (unsigned*)p;               // 8704 * 1024 * 4 = 35.7 MB

    prep_kernel<<<dim3(8, NB), 256, 0, stream>>>(S, T, targets, idx, npos,
                                                 sumS, sumT, out, Ps, Pt, ns, nt);
    const int nblk = 136 * NB;           // 16x16 upper-tri tiles x batches
    dist_kernel<<<nblk, 64, 0, stream>>>(Ps, Pt, ns, nt, npos, sumS, sumT, D);
    huber_kernel<<<nblk, 64, 0, stream>>>(D, npos, sumS, sumT, out);
}

// Round 10
// 137.435 us; speedup vs baseline: 1.2904x; 1.2904x over previous
//
#include <hip/hip_runtime.h>
#include <hip/hip_bf16.h>
#include <hip/hip_fp16.h>
#include <math.h>

#define NB 64
#define CC 512
#define LL 256

typedef __attribute__((ext_vector_type(4))) float floatx4;
typedef __attribute__((ext_vector_type(8))) short short8;

static __device__ __forceinline__ unsigned f2bf2(float x, float y) {
    __hip_bfloat162 h = __float22bfloat162_rn(make_float2(x, y));
    union { __hip_bfloat162 h; unsigned u; } c; c.h = h;
    return c.u;   // low 16 = x, high 16 = y
}
static __device__ __forceinline__ unsigned f2h(float x) {
    __half h = __float2half_rn(x);
    union { __half h; unsigned short u; } c; c.h = h;
    return (unsigned)c.u;
}
static __device__ __forceinline__ float h2f(unsigned u) {
    union { unsigned short u; __half h; } c; c.u = (unsigned short)u;
    return __half2float(c.h);
}

// ---------------- K0: per-batch ballot compaction -> global idx/npos, zero sums ----
__global__ __launch_bounds__(256) void prep_kernel(
    const int* __restrict__ targets,
    int* __restrict__ idx, int* __restrict__ npos,
    float* __restrict__ sumS, float* __restrict__ sumT, float* __restrict__ out)
{
    const int n = blockIdx.x, tid = threadIdx.x;
    __shared__ int s_cnt[8], s_off[8];
    const int w = tid >> 6, lane = tid & 63;
    const int* tg = targets + n * CC;
    const bool p0 = tg[tid] != 0;
    const bool p1 = tg[tid + 256] != 0;
    const unsigned long long m0 = __ballot(p0);
    const unsigned long long m1 = __ballot(p1);
    if (lane == 0) { s_cnt[w] = __popcll(m0); s_cnt[4 + w] = __popcll(m1); }
    __syncthreads();
    if (tid == 0) {
        int a = 0;
        for (int i = 0; i < 8; ++i) { s_off[i] = a; a += s_cnt[i]; }
        npos[n] = a;
        sumS[n] = 0.0f; sumT[n] = 0.0f;
        if (n == 0) out[0] = 0.0f;
    }
    __syncthreads();
    const unsigned long long below = (1ull << lane) - 1ull;
    if (p0) idx[n * CC + s_off[w] + __popcll(m0 & below)] = tid;
    if (p1) idx[n * CC + s_off[4 + w] + __popcll(m1 & below)] = tid + 256;
}

// decode linear t -> upper-tri (tI,tJ) of a u x u tile grid
static __device__ __forceinline__ bool decode_tile(int t, int u, int& tI, int& tJ) {
    if (t >= (u * (u + 1)) >> 1) return false;
    tI = 0;
    while (t >= u - tI) { t -= u - tI; ++tI; }
    tJ = tI + t;
    return true;
}

// ---------------- K1: dual MFMA Gram + distances, dbuf LDS (1 barrier/chunk) --------
// bx = n*36 + t; active tiles decoded from npos (inactive blocks exit after 2 loads).
__global__ __launch_bounds__(256) void dist_kernel(
    const float* __restrict__ S, const float* __restrict__ T,
    const int* __restrict__ idx, const int* __restrict__ npos,
    float* __restrict__ sumS, float* __restrict__ sumT,
    unsigned* __restrict__ D)
{
    const int bx = blockIdx.x;
    const int n = bx / 36;
    const int np = npos[n];
    if (np < 2) return;
    int tI, tJ;
    if (!decode_tile(bx - n * 36, (np + 63) >> 6, tI, tJ)) return;
    const bool diag = (tI == tJ);

    // double-buffered bf16 chunk tiles; row stride 40 halves (pad 8), rows 80 B
    __shared__ __align__(16) unsigned short lds[4][2][64][40];   // 40 KiB
    __shared__ float s_norm[4][64];
    __shared__ float redA[4], redB[4];

    const int tid = threadIdx.x;
    const int w = tid >> 6, lane = tid & 63;

    // wave w stages buffer w: 0=S-A, 1=S-B, 2=T-A, 3=T-B (diag: B aliases A)
    const bool stager = (!diag) || ((w & 1) == 0);
    const char* Pbase = (const char*)(((w >> 1) ? T : S) + (size_t)n * CC * LL);
    const int tileBase = ((w & 1) ? tJ : tI) * 64;
    const int r8 = lane >> 3, c8 = lane & 7;   // 8 lanes/row, 128 B per row-chunk
    unsigned off_[8];
    #pragma unroll
    for (int i = 0; i < 8; ++i) {
        const int gk = tileBase + r8 + 8 * i;
        const int row = idx[n * CC + ((gk < np) ? gk : 0)];
        off_[i] = (unsigned)(row * LL * 4 + c8 * 16);
    }

    float4 pre[8];
    float nprt[8];
    #pragma unroll
    for (int i = 0; i < 8; ++i) nprt[i] = 0.0f;
    if (stager) {
        #pragma unroll
        for (int i = 0; i < 8; ++i) pre[i] = *(const float4*)(Pbase + off_[i]);
    }

    const int m16 = lane & 15, quad = lane >> 4;
    const int bufB = diag ? 0 : 1;
    const int wrow = w * 16;

    floatx4 accS[4], accT[4];
    #pragma unroll
    for (int c = 0; c < 4; ++c) {
        accS[c][0] = 0; accS[c][1] = 0; accS[c][2] = 0; accS[c][3] = 0;
        accT[c][0] = 0; accT[c][1] = 0; accT[c][2] = 0; accT[c][3] = 0;
    }

    for (int kk = 0; kk < 8; ++kk) {
        const int pb = kk & 1;
        if (stager) {
            // safe: chunk kk-2's reads of buf pb drained at barrier kk-1 (lgkmcnt)
            #pragma unroll
            for (int i = 0; i < 8; ++i) {
                nprt[i] += pre[i].x * pre[i].x + pre[i].y * pre[i].y +
                           pre[i].z * pre[i].z + pre[i].w * pre[i].w;
                *(uint2*)&lds[w][pb][r8 + 8 * i][c8 * 4] =
                    make_uint2(f2bf2(pre[i].x, pre[i].y), f2bf2(pre[i].z, pre[i].w));
            }
        }
        __syncthreads();   // single barrier per chunk
        if (stager && kk < 7) {               // prefetch next chunk during MFMA
            #pragma unroll
            for (int i = 0; i < 8; ++i)
                pre[i] = *(const float4*)(Pbase + off_[i] + (kk + 1) * 128);
        }
        const int aoff = (wrow + m16) * 40 + quad * 8;
        const short8 a_s = *(const short8*)(&lds[0][pb][0][0] + aoff);
        const short8 a_t = *(const short8*)(&lds[2][pb][0][0] + aoff);
        #pragma unroll
        for (int c = 0; c < 4; ++c) {
            const int boff = (c * 16 + m16) * 40 + quad * 8;
            const short8 b_s = *(const short8*)(&lds[bufB][pb][0][0] + boff);
            const short8 b_t = *(const short8*)(&lds[2 + bufB][pb][0][0] + boff);
            accS[c] = __builtin_amdgcn_mfma_f32_16x16x32_bf16(a_s, b_s, accS[c], 0, 0, 0);
            accT[c] = __builtin_amdgcn_mfma_f32_16x16x32_bf16(a_t, b_t, accT[c], 0, 0, 0);
        }
    }

    // ---- inline norms: reduce the 8 lanes (c8) sharing each staged row ----
    if (stager) {
        #pragma unroll
        for (int i = 0; i < 8; ++i) {
            float v = nprt[i];
            v += __shfl_xor(v, 1); v += __shfl_xor(v, 2); v += __shfl_xor(v, 4);
            if (c8 == 0) s_norm[w][r8 + 8 * i] = v;
        }
    }
    __syncthreads();

    // ---- distances; C/D layout: col=lane&15, row=quad*4+reg ----
    unsigned* Dn = D + ((size_t)bx << 12);    // 64x64 entries
    float l0 = 0.0f, l1 = 0.0f;
    #pragma unroll
    for (int c = 0; c < 4; ++c) {
        const int colL = c * 16 + m16;
        const int gj = tJ * 64 + colL;
        const float nBs = s_norm[bufB][colL];
        const float nBt = s_norm[2 + bufB][colL];
        #pragma unroll
        for (int r = 0; r < 4; ++r) {
            const int rowL = wrow + quad * 4 + r;
            const int gi = tI * 64 + rowL;
            const float ds = sqrtf(fmaxf(s_norm[0][rowL] + nBs - 2.0f * accS[c][r], 1e-12f));
            const float dt = sqrtf(fmaxf(s_norm[2][rowL] + nBt - 2.0f * accT[c][r], 1e-12f));
            if (gi < np && gj < np && gi != gj) { l0 += ds; l1 += dt; }
            Dn[rowL * 64 + colL] = f2h(ds) | (f2h(dt) << 16);
        }
    }

    #pragma unroll
    for (int o = 32; o; o >>= 1) { l0 += __shfl_down(l0, o); l1 += __shfl_down(l1, o); }
    if (lane == 0) { redA[w] = l0; redB[w] = l1; }
    __syncthreads();
    if (tid == 0) {
        const float wgt = diag ? 1.0f : 2.0f;  // off-diag tiles mirror-counted
        atomicAdd(&sumS[n], wgt * (redA[0] + redA[1] + redA[2] + redA[3]));
        atomicAdd(&sumT[n], wgt * (redB[0] + redB[1] + redB[2] + redB[3]));
    }
}

// ---------------- K2: streaming Huber over packed (ds, dt) ----------------
// Same bx mapping as K1: block reads the D tile its own XCD just wrote.
__global__ __launch_bounds__(256) void huber_kernel(
    const unsigned* __restrict__ D, const int* __restrict__ npos,
    const float* __restrict__ sumS, const float* __restrict__ sumT,
    float* __restrict__ out)
{
    const int bx = blockIdx.x;
    const int n = bx / 36;
    const int np = npos[n];
    if (np < 2) return;
    int tI, tJ;
    if (!decode_tile(bx - n * 36, (np + 63) >> 6, tI, tJ)) return;

    const float cnt = (float)np * (float)(np - 1);
    const float inv_ms = cnt / sumS[n];
    const float inv_mt = cnt / sumT[n];

    const uint4* Dn = (const uint4*)(D + ((size_t)bx << 12));
    const int tid = threadIdx.x;

    float h = 0.0f;
    #pragma unroll
    for (int it = 0; it < 4; ++it) {
        const int e4 = it * 256 + tid;        // uint4 index; element = e4*4
        const uint4 v = Dn[e4];
        const unsigned vv[4] = { v.x, v.y, v.z, v.w };
        const int e0 = e4 * 4;
        #pragma unroll
        for (int k = 0; k < 4; ++k) {
            const int e = e0 + k;
            const int gi = tI * 64 + (e >> 6);
            const int gj = tJ * 64 + (e & 63);
            if (gi < np && gj < np && gi != gj) {
                const float ds = h2f(vv[k] & 0xffffu);
                const float dt = h2f(vv[k] >> 16);
                const float diff = ds * inv_ms - dt * inv_mt;
                const float ad = fabsf(diff);
                h += (ad < 1.0f) ? 0.5f * diff * diff : ad - 0.5f;
            }
        }
    }

    #pragma unroll
    for (int o = 32; o; o >>= 1) h += __shfl_down(h, o);
    __shared__ float red[4];
    const int w = tid >> 6, lane = tid & 63;
    if (lane == 0) red[w] = h;
    __syncthreads();
    if (tid == 0) {
        const float wgt = (tI == tJ) ? 1.0f : 2.0f;
        atomicAdd(out, wgt * (red[0] + red[1] + red[2] + red[3]) / (float)np);
    }
}

extern "C" void kernel_launch(void* const* d_in, const int* in_sizes, int n_in,
                              void* d_out, int out_size, void* d_ws, size_t ws_size,
                              hipStream_t stream) {
    const float* S = (const float*)d_in[0];
    const float* T = (const float*)d_in[1];
    const int* targets = (const int*)d_in[2];
    float* out = (float*)d_out;

    char* p = (char*)d_ws;
    int* idx = (int*)p;        p += (size_t)NB * CC * 4;
    int* npos = (int*)p;       p += NB * 4;
    float* sumS = (float*)p;   p += NB * 4;
    float* sumT = (float*)p;   p += NB * 4;
    p = (char*)(((size_t)p + 255) & ~(size_t)255);
    unsigned* D = (unsigned*)p;                 // 2304 * 4096 * 4 = 37.7 MB

    prep_kernel<<<NB, 256, 0, stream>>>(targets, idx, npos, sumS, sumT, out);
    dist_kernel<<<NB * 36, 256, 0, stream>>>(S, T, idx, npos, sumS, sumT, D);
    huber_kernel<<<NB * 36, 256, 0, stream>>>(D, npos, sumS, sumT, out);
}

// Round 11
// 124.817 us; speedup vs baseline: 1.4209x; 1.1011x over previous
//
#include <hip/hip_runtime.h>
#include <hip/hip_bf16.h>
#include <hip/hip_fp16.h>
#include <math.h>

#define NB 64
#define CC 512
#define LL 256

typedef __attribute__((ext_vector_type(4))) float floatx4;
typedef __attribute__((ext_vector_type(8))) short short8;

static __device__ __forceinline__ unsigned f2bf2(float x, float y) {
    __hip_bfloat162 h = __float22bfloat162_rn(make_float2(x, y));
    union { __hip_bfloat162 h; unsigned u; } c; c.h = h;
    return c.u;   // low 16 = x, high 16 = y
}
static __device__ __forceinline__ unsigned short f2h(float x) {
    __half h = __float2half_rn(x);
    union { __half h; unsigned short u; } c; c.h = h;
    return c.u;
}
static __device__ __forceinline__ float h2f(unsigned u) {
    union { unsigned short u; __half h; } c; c.u = (unsigned short)u;
    return __half2float(c.h);
}

// ---------------- K0: per-batch ballot compaction -> global idx/npos, zero sums ----
__global__ __launch_bounds__(256) void prep_kernel(
    const int* __restrict__ targets,
    int* __restrict__ idx, int* __restrict__ npos,
    float* __restrict__ sumS, float* __restrict__ sumT, float* __restrict__ out)
{
    const int n = blockIdx.x, tid = threadIdx.x;
    __shared__ int s_cnt[8], s_off[8];
    const int w = tid >> 6, lane = tid & 63;
    const int* tg = targets + n * CC;
    const bool p0 = tg[tid] != 0;
    const bool p1 = tg[tid + 256] != 0;
    const unsigned long long m0 = __ballot(p0);
    const unsigned long long m1 = __ballot(p1);
    if (lane == 0) { s_cnt[w] = __popcll(m0); s_cnt[4 + w] = __popcll(m1); }
    __syncthreads();
    if (tid == 0) {
        int a = 0;
        for (int i = 0; i < 8; ++i) { s_off[i] = a; a += s_cnt[i]; }
        npos[n] = a;
        sumS[n] = 0.0f; sumT[n] = 0.0f;
        if (n == 0) out[0] = 0.0f;
    }
    __syncthreads();
    const unsigned long long below = (1ull << lane) - 1ull;
    if (p0) idx[n * CC + s_off[w] + __popcll(m0 & below)] = tid;
    if (p1) idx[n * CC + s_off[4 + w] + __popcll(m1 & below)] = tid + 256;
}

// decode linear t -> upper-tri (tI,tJ) of a u x u tile grid
static __device__ __forceinline__ bool decode_tile(int t, int u, int& tI, int& tJ) {
    if (t >= (u * (u + 1)) >> 1) return false;
    tI = 0;
    while (t >= u - tI) { t -= u - tI; ++tI; }
    tJ = tI + t;
    return true;
}

// ---------------- K1: single-matrix MFMA Gram + distances ----------------
// bx = (t*2+mat)*64 + n  =>  bx % 8 == n % 8 (XCD-clustered per batch).
// Each block computes ONE matrix's (S or T) 64x64 distance tile: all 4 waves stage
// (2 float4 rounds/lane/chunk), dbuf LDS with 1 barrier/chunk, 4 MFMA/chunk/wave.
__global__ __launch_bounds__(256) void dist_kernel(
    const float* __restrict__ S, const float* __restrict__ T,
    const int* __restrict__ idx, const int* __restrict__ npos,
    float* __restrict__ sumS, float* __restrict__ sumT,
    unsigned short* __restrict__ Ds, unsigned short* __restrict__ Dt)
{
    const int bx = blockIdx.x;
    const int n = bx & (NB - 1);
    const int q = bx >> 6;
    const int mat = q & 1, t = q >> 1;
    const int np = npos[n];
    if (np < 2) return;
    int tI, tJ;
    if (!decode_tile(t, (np + 63) >> 6, tI, tJ)) return;
    const bool diag = (tI == tJ);

    // bf16 tiles [A/B][dbuf][row][40 halves] = 20.5 KB
    __shared__ __align__(16) unsigned short lds[2][2][64][40];
    __shared__ float s_norm[2][64];
    __shared__ float red[4];

    const int tid = threadIdx.x;
    const int w = tid >> 6, lane = tid & 63;

    const float* P = (mat ? T : S) + (size_t)n * CC * LL;
    unsigned short* Dout = (mat ? Dt : Ds) + (((size_t)t * NB + n) << 12);
    float* sumP = mat ? sumT : sumS;

    // staging: logical rows 0..127 = A rows 0..63 then B rows 64..127 (diag: A only)
    const int srow = w * 32 + (lane >> 1);
    const int half = lane & 1;                 // which 64 B half of the row's 128 B chunk
    const bool stager = diag ? (srow < 64) : true;
    const int ab = srow >> 6, rloc = srow & 63;
    const int gk = (ab ? tJ : tI) * 64 + rloc;
    const int row = idx[n * CC + ((gk < np) ? gk : 0)];
    const char* rp = (const char*)P + (size_t)row * (LL * 4) + half * 64;

    float4 pre[4];
    float nsum = 0.0f;
    if (stager) {
        #pragma unroll
        for (int i = 0; i < 4; ++i) pre[i] = *(const float4*)(rp + i * 16);
    }

    const int m16 = lane & 15, quad = lane >> 4;
    const int bufB = diag ? 0 : 1;
    const int wrow = w * 16;

    floatx4 acc[4];
    #pragma unroll
    for (int c = 0; c < 4; ++c) { acc[c][0] = 0; acc[c][1] = 0; acc[c][2] = 0; acc[c][3] = 0; }

    for (int kk = 0; kk < 8; ++kk) {
        const int pb = kk & 1;
        if (stager) {
            // safe: chunk kk-2's reads of buf pb drained at barrier kk-1 (lgkmcnt)
            #pragma unroll
            for (int i = 0; i < 4; ++i)
                nsum += pre[i].x * pre[i].x + pre[i].y * pre[i].y +
                        pre[i].z * pre[i].z + pre[i].w * pre[i].w;
            unsigned short* dst = &lds[ab][pb][rloc][half * 16];
            *(uint2*)(dst + 0)  = make_uint2(f2bf2(pre[0].x, pre[0].y), f2bf2(pre[0].z, pre[0].w));
            *(uint2*)(dst + 4)  = make_uint2(f2bf2(pre[1].x, pre[1].y), f2bf2(pre[1].z, pre[1].w));
            *(uint2*)(dst + 8)  = make_uint2(f2bf2(pre[2].x, pre[2].y), f2bf2(pre[2].z, pre[2].w));
            *(uint2*)(dst + 12) = make_uint2(f2bf2(pre[3].x, pre[3].y), f2bf2(pre[3].z, pre[3].w));
        }
        __syncthreads();   // single barrier per chunk
        if (stager && kk < 7) {                // prefetch next chunk during MFMA
            #pragma unroll
            for (int i = 0; i < 4; ++i)
                pre[i] = *(const float4*)(rp + (kk + 1) * 128 + i * 16);
        }
        const short8 a = *(const short8*)&lds[0][pb][wrow + m16][quad * 8];
        #pragma unroll
        for (int c = 0; c < 4; ++c) {
            const short8 b = *(const short8*)&lds[bufB][pb][c * 16 + m16][quad * 8];
            acc[c] = __builtin_amdgcn_mfma_f32_16x16x32_bf16(a, b, acc[c], 0, 0, 0);
        }
    }

    // ---- inline norms: 2 lanes share each staged row ----
    if (stager) {
        const float v = nsum + __shfl_xor(nsum, 1);
        if (half == 0) s_norm[ab][rloc] = v;
    }
    __syncthreads();

    // ---- distances; C/D layout: col=lane&15, row=quad*4+reg ----
    float l0 = 0.0f;
    #pragma unroll
    for (int c = 0; c < 4; ++c) {
        const int colL = c * 16 + m16;
        const int gj = tJ * 64 + colL;
        const float nB = s_norm[bufB][colL];
        #pragma unroll
        for (int r = 0; r < 4; ++r) {
            const int rowL = wrow + quad * 4 + r;
            const int gi = tI * 64 + rowL;
            const float d = sqrtf(fmaxf(s_norm[0][rowL] + nB - 2.0f * acc[c][r], 1e-12f));
            if (gi < np && gj < np && gi != gj) l0 += d;
            Dout[rowL * 64 + colL] = f2h(d);
        }
    }

    #pragma unroll
    for (int o = 32; o; o >>= 1) l0 += __shfl_down(l0, o);
    if (lane == 0) red[w] = l0;
    __syncthreads();
    if (tid == 0) {
        const float wgt = diag ? 1.0f : 2.0f;  // off-diag tiles mirror-counted
        atomicAdd(sumP + n, wgt * (red[0] + red[1] + red[2] + red[3]));
    }
}

// ---------------- K2: streaming Huber over fp16 Ds/Dt ----------------
// bx = t*64 + n: same XCD as the dist blocks that wrote this tile.
__global__ __launch_bounds__(256) void huber_kernel(
    const unsigned short* __restrict__ Ds, const unsigned short* __restrict__ Dt,
    const int* __restrict__ npos,
    const float* __restrict__ sumS, const float* __restrict__ sumT,
    float* __restrict__ out)
{
    const int bx = blockIdx.x;
    const int n = bx & (NB - 1), t = bx >> 6;
    const int np = npos[n];
    if (np < 2) return;
    int tI, tJ;
    if (!decode_tile(t, (np + 63) >> 6, tI, tJ)) return;

    const float cnt = (float)np * (float)(np - 1);
    const float inv_ms = cnt / sumS[n];
    const float inv_mt = cnt / sumT[n];

    const size_t slot = ((size_t)t * NB + n) << 12;
    const uint4* ps = (const uint4*)(Ds + slot);   // 4096 halves = 512 uint4
    const uint4* pt = (const uint4*)(Dt + slot);
    const int tid = threadIdx.x;

    float h = 0.0f;
    #pragma unroll
    for (int it = 0; it < 2; ++it) {
        const int g = it * 256 + tid;              // uint4 group; 8 entries each
        const uint4 a = ps[g];
        const uint4 b = pt[g];
        const unsigned aw[4] = { a.x, a.y, a.z, a.w };
        const unsigned bw[4] = { b.x, b.y, b.z, b.w };
        const int e0 = g * 8;
        #pragma unroll
        for (int k = 0; k < 8; ++k) {
            const int e = e0 + k;
            const int gi = tI * 64 + (e >> 6);
            const int gj = tJ * 64 + (e & 63);
            if (gi < np && gj < np && gi != gj) {
                const unsigned wa = aw[k >> 1], wb = bw[k >> 1];
                const float ds = h2f((k & 1) ? (wa >> 16) : (wa & 0xffffu));
                const float dt = h2f((k & 1) ? (wb >> 16) : (wb & 0xffffu));
                const float diff = ds * inv_ms - dt * inv_mt;
                const float ad = fabsf(diff);
                h += (ad < 1.0f) ? 0.5f * diff * diff : ad - 0.5f;
            }
        }
    }

    #pragma unroll
    for (int o = 32; o; o >>= 1) h += __shfl_down(h, o);
    __shared__ float red[4];
    const int w = tid >> 6, lane = tid & 63;
    if (lane == 0) red[w] = h;
    __syncthreads();
    if (tid == 0) {
        const float wgt = (tI == tJ) ? 1.0f : 2.0f;
        atomicAdd(out, wgt * (red[0] + red[1] + red[2] + red[3]) / (float)np);
    }
}

extern "C" void kernel_launch(void* const* d_in, const int* in_sizes, int n_in,
                              void* d_out, int out_size, void* d_ws, size_t ws_size,
                              hipStream_t stream) {
    const float* S = (const float*)d_in[0];
    const float* T = (const float*)d_in[1];
    const int* targets = (const int*)d_in[2];
    float* out = (float*)d_out;

    char* p = (char*)d_ws;
    int* idx = (int*)p;        p += (size_t)NB * CC * 4;
    int* npos = (int*)p;       p += NB * 4;
    float* sumS = (float*)p;   p += NB * 4;
    float* sumT = (float*)p;   p += NB * 4;
    p = (char*)(((size_t)p + 255) & ~(size_t)255);
    unsigned short* Ds = (unsigned short*)p;   p += (size_t)36 * NB * 4096 * 2;  // 18.9 MB
    unsigned short* Dt = (unsigned short*)p;                                      // 18.9 MB

    prep_kernel<<<NB, 256, 0, stream>>>(targets, idx, npos, sumS, sumT, out);
    dist_kernel<<<72 * NB, 256, 0, stream>>>(S, T, idx, npos, sumS, sumT, Ds, Dt);
    huber_kernel<<<36 * NB, 256, 0, stream>>>(Ds, Dt, npos, sumS, sumT, out);
}